// Round 2
// baseline (1134.792 us; speedup 1.0000x reference)
//
#include <hip/hip_runtime.h>

#define BB 128
#define SS 1000
#define HH 256
#define H3 768
#define H2 512

typedef unsigned short u16;
typedef short short8 __attribute__((ext_vector_type(8)));
typedef float floatx4 __attribute__((ext_vector_type(4)));
typedef u16 ushort4v __attribute__((ext_vector_type(4)));

__device__ __forceinline__ u16 f2bf(float f) {
    unsigned int x = __float_as_uint(f);
    x += 0x7FFFu + ((x >> 16) & 1u);   // round-to-nearest-even
    return (u16)(x >> 16);
}

// tanh via one v_exp + one v_rcp; exact saturation at +-inf.
__device__ __forceinline__ float fast_tanh(float x) {
    float t = __expf(2.0f * x);
    return 1.0f - 2.0f * __builtin_amdgcn_rcpf(t + 1.0f);
}

__device__ __forceinline__ float sigmoidf(float x) {
    return __builtin_amdgcn_rcpf(1.0f + __expf(-x));
}

// ---------------------------------------------------------------------------
// Pre-convert attn_W [768x768] and dec_W [512x512] f32 -> bf16 in workspace.
// 4 elements/thread; 589824 and 262144 both divisible by 4 (no straddle).
// ---------------------------------------------------------------------------
__global__ __launch_bounds__(256) void k_prep(
    const float* __restrict__ aW, const float* __restrict__ dW,
    u16* __restrict__ aWb, u16* __restrict__ dWb)
{
    int idx = (blockIdx.x * 256 + threadIdx.x) * 4;
    const float* src;
    u16* dst;
    if (idx < 589824) { src = aW + idx; dst = aWb + idx; }
    else              { src = dW + (idx - 589824); dst = dWb + (idx - 589824); }
    float4 v = *(const float4*)src;
    ushort4v o = { f2bf(v.x), f2bf(v.y), f2bf(v.z), f2bf(v.w) };
    *(ushort4v*)dst = o;
}

// ---------------------------------------------------------------------------
// Kernel: embed + GRU cell + hidden out + Wh[b,j] = attn_W[j,512:768]·h_new[b]
// grid = B blocks, 256 threads (one per hidden unit). All f32 VALU.
// ---------------------------------------------------------------------------
__global__ __launch_bounds__(256) void k_gru(
    const float* __restrict__ dec, const float* __restrict__ h0,
    const float* __restrict__ embW, const float* __restrict__ embb,
    const float* __restrict__ Wih, const float* __restrict__ Whh,
    const float* __restrict__ bih, const float* __restrict__ bhh,
    const float* __restrict__ attnW,
    float* __restrict__ Wh, float* __restrict__ out_hidden)
{
    const int b = blockIdx.x, t = threadIdx.x;
    __shared__ float emb_s[HH], h_s[HH], hn_s[HH];

    const float d0 = dec[b * 2 + 0], d1 = dec[b * 2 + 1];
    emb_s[t] = d0 * embW[t * 2 + 0] + d1 * embW[t * 2 + 1] + embb[t];
    h_s[t] = h0[b * HH + t];
    __syncthreads();

    auto dotrow = [&](const float* Wr, const float* xs) -> float {
        float acc = 0.f;
        const float4* p = (const float4*)Wr;
#pragma unroll 8
        for (int c = 0; c < HH / 4; ++c) {
            float4 w = p[c];
            acc += w.x * xs[c * 4 + 0] + w.y * xs[c * 4 + 1]
                 + w.z * xs[c * 4 + 2] + w.w * xs[c * 4 + 3];
        }
        return acc;
    };

    // gates for hidden unit t (rows t, 256+t, 512+t): PyTorch order r,z,n
    float gr = dotrow(Wih + (size_t)t * HH, emb_s) + bih[t]
             + dotrow(Whh + (size_t)t * HH, h_s) + bhh[t];
    float r = sigmoidf(gr);

    float gz = dotrow(Wih + (size_t)(HH + t) * HH, emb_s) + bih[HH + t]
             + dotrow(Whh + (size_t)(HH + t) * HH, h_s) + bhh[HH + t];
    float z = sigmoidf(gz);

    float xn = dotrow(Wih + (size_t)(2 * HH + t) * HH, emb_s) + bih[2 * HH + t];
    float hn = dotrow(Whh + (size_t)(2 * HH + t) * HH, h_s) + bhh[2 * HH + t];
    float n = fast_tanh(xn + r * hn);

    float hv = (1.0f - z) * n + z * h_s[t];
    out_hidden[b * HH + t] = hv;
    hn_s[t] = hv;
    __syncthreads();

    // Wh[b,j] = sum_k attn_W[j, 512+k] * h_new[b,k], j = t, t+256, t+512
#pragma unroll
    for (int rr = 0; rr < 3; ++rr) {
        int j = t + rr * HH;
        Wh[b * H3 + j] = dotrow(attnW + (size_t)j * H3 + 2 * HH, hn_s);
    }
}

// ---------------------------------------------------------------------------
// Score GEMM: out[b,s] = sum_j vj[j] * tanh( (A @ Wb[:, :K]^T)[s,j] + addj[b,j] )
// A rows: k<256 from A1 (f32), k>=256 from A2 (f32); converted to bf16 in-reg.
// Wb is pre-converted bf16. grid = (8 s-tiles of 128, B), block = 256.
// Each wave covers 2 m-tiles of 16 rows (B fragment reused x2).
// mfma_f32_16x16x32_bf16: A[m=lane&15][k=quad*8+j], D: col=lane&15, row=quad*4+reg
// ---------------------------------------------------------------------------
template <int KSTEPS, int NTILES, int WSTRIDE>
__global__ __launch_bounds__(256) void k_scores(
    const float* __restrict__ A1, const float* __restrict__ A2,
    const u16* __restrict__ Wb, const float* __restrict__ addj,
    const float* __restrict__ vj, float* __restrict__ out)
{
    const int b = blockIdx.y, t = threadIdx.x;
    const int wave = t >> 6, lane = t & 63;
    const int q = lane >> 4, c = lane & 15;
    const int s_base = blockIdx.x * 128 + wave * 32;   // 2 m-tiles of 16 rows
    const int kb = q * 8;

    short8 afrag[2][KSTEPS];
#pragma unroll
    for (int mt = 0; mt < 2; ++mt) {
        int row = s_base + mt * 16 + c;
        if (row > SS - 1) row = SS - 1;            // tail clamp; writes guarded
        const size_t abase = (size_t)(b * SS + row) * HH;
#pragma unroll
        for (int ks = 0; ks < KSTEPS; ++ks) {
            int k = ks * 32 + kb;                  // never straddles 256 (8|kb)
            const float* src = (k < HH) ? (A1 + abase + k) : (A2 + abase + (k - HH));
            float4 u0 = *(const float4*)src;
            float4 u1 = *(const float4*)(src + 4);
            short8 f;
            f[0] = (short)f2bf(u0.x); f[1] = (short)f2bf(u0.y);
            f[2] = (short)f2bf(u0.z); f[3] = (short)f2bf(u0.w);
            f[4] = (short)f2bf(u1.x); f[5] = (short)f2bf(u1.y);
            f[6] = (short)f2bf(u1.z); f[7] = (short)f2bf(u1.w);
            afrag[mt][ks] = f;
        }
    }

    float p[2][4] = {{0.f, 0.f, 0.f, 0.f}, {0.f, 0.f, 0.f, 0.f}};
    for (int jt = 0; jt < NTILES; ++jt) {
        const int j = jt * 16 + c;
        floatx4 acc0 = {0.f, 0.f, 0.f, 0.f};
        floatx4 acc1 = {0.f, 0.f, 0.f, 0.f};
        const u16* wrow = Wb + (size_t)j * WSTRIDE + kb;
#pragma unroll
        for (int ks = 0; ks < KSTEPS; ++ks) {
            short8 wf = *(const short8*)(wrow + ks * 32);
            acc0 = __builtin_amdgcn_mfma_f32_16x16x32_bf16(afrag[0][ks], wf, acc0, 0, 0, 0);
            acc1 = __builtin_amdgcn_mfma_f32_16x16x32_bf16(afrag[1][ks], wf, acc1, 0, 0, 0);
        }
        const float aj = addj[b * (NTILES * 16) + j];
        const float vv = vj[j];
#pragma unroll
        for (int r = 0; r < 4; ++r) {
            p[0][r] += fast_tanh(acc0[r] + aj) * vv;
            p[1][r] += fast_tanh(acc1[r] + aj) * vv;
        }
    }

    // reduce over the 16 lanes of each quad (the j-columns)
#pragma unroll
    for (int mt = 0; mt < 2; ++mt)
#pragma unroll
        for (int r = 0; r < 4; ++r)
#pragma unroll
            for (int off = 1; off < 16; off <<= 1)
                p[mt][r] += __shfl_xor(p[mt][r], off, 64);

    if (c == 0) {
#pragma unroll
        for (int mt = 0; mt < 2; ++mt) {
            const int srow = s_base + mt * 16 + q * 4;
#pragma unroll
            for (int r = 0; r < 4; ++r)
                if (srow + r < SS) out[b * SS + srow + r] = p[mt][r];
        }
    }
}

// ---------------------------------------------------------------------------
// Softmax over S per batch row; f32 in, f32 out.
// ---------------------------------------------------------------------------
__global__ __launch_bounds__(256) void k_softmax(
    const float* __restrict__ in, float* __restrict__ outf)
{
    const int b = blockIdx.x, t = threadIdx.x;
    __shared__ float red[4];
    const float* rowp = in + b * SS;

    float m = -1e30f;
    for (int s = t; s < SS; s += 256) m = fmaxf(m, rowp[s]);
#pragma unroll
    for (int off = 32; off >= 1; off >>= 1) m = fmaxf(m, __shfl_xor(m, off, 64));
    if ((t & 63) == 0) red[t >> 6] = m;
    __syncthreads();
    m = fmaxf(fmaxf(red[0], red[1]), fmaxf(red[2], red[3]));

    float sum = 0.f;
    for (int s = t; s < SS; s += 256) sum += __expf(rowp[s] - m);
#pragma unroll
    for (int off = 32; off >= 1; off >>= 1) sum += __shfl_xor(sum, off, 64);
    __syncthreads();
    if ((t & 63) == 0) red[t >> 6] = sum;
    __syncthreads();
    sum = red[0] + red[1] + red[2] + red[3];

    const float inv = 1.0f / sum;
    for (int s = t; s < SS; s += 256)
        outf[b * SS + s] = __expf(rowp[s] - m) * inv;
}

// ---------------------------------------------------------------------------
// context[b,h] = sum_s attn[b,s]*static[b,s,h]; Dc[b,j] = dec_W[j,256:512]·context[b]
// grid = B blocks, 256 threads (one per h; coalesced over h).
// ---------------------------------------------------------------------------
__global__ __launch_bounds__(256) void k_context(
    const float* __restrict__ attn, const float* __restrict__ stat,
    const float* __restrict__ decW, float* __restrict__ Dc)
{
    const int b = blockIdx.x, t = threadIdx.x;
    __shared__ float attn_s[SS];
    __shared__ float ctx_s[HH];
    for (int s = t; s < SS; s += 256) attn_s[s] = attn[b * SS + s];
    __syncthreads();

    float acc = 0.f;
    const float* base = stat + (size_t)b * SS * HH + t;
#pragma unroll 4
    for (int s = 0; s < SS; ++s) acc += attn_s[s] * base[(size_t)s * HH];
    ctx_s[t] = acc;
    __syncthreads();

#pragma unroll
    for (int rr = 0; rr < 2; ++rr) {
        int j = t + rr * 256;
        float a2 = 0.f;
        const float4* p = (const float4*)(decW + (size_t)j * H2 + HH);
#pragma unroll 8
        for (int cc = 0; cc < HH / 4; ++cc) {
            float4 w = p[cc];
            a2 += w.x * ctx_s[cc * 4 + 0] + w.y * ctx_s[cc * 4 + 1]
                + w.z * ctx_s[cc * 4 + 2] + w.w * ctx_s[cc * 4 + 3];
        }
        Dc[b * H2 + j] = a2;
    }
}

// ---------------------------------------------------------------------------
extern "C" void kernel_launch(void* const* d_in, const int* in_sizes, int n_in,
                              void* d_out, int out_size, void* d_ws, size_t ws_size,
                              hipStream_t stream)
{
    const float* dec   = (const float*)d_in[0];
    const float* h0    = (const float*)d_in[1];
    const float* stat  = (const float*)d_in[2];
    const float* dyn   = (const float*)d_in[3];
    const float* embW  = (const float*)d_in[4];
    const float* embb  = (const float*)d_in[5];
    const float* Wih   = (const float*)d_in[6];
    const float* Whh   = (const float*)d_in[7];
    const float* bih   = (const float*)d_in[8];
    const float* bhh   = (const float*)d_in[9];
    const float* attnW = (const float*)d_in[10];
    const float* attnv = (const float*)d_in[11];
    const float* decW  = (const float*)d_in[12];
    const float* decv  = (const float*)d_in[13];

    float* out        = (float*)d_out;
    float* out_probs  = out;                 // [B, S]   = 128000
    float* out_hidden = out + BB * SS;       // [1, B, H] = 32768

    // workspace: bf16 weight copies first, then f32 scratch (16B-aligned split)
    u16* wsb     = (u16*)d_ws;
    u16* attnWb  = wsb;                      // 768*768 = 589824 u16
    u16* decWb   = wsb + 589824;             // 512*512 = 262144 u16
    float* wsf   = (float*)(wsb + 851968);   // byte offset 1703936 (16B-aligned)
    float* Wh      = wsf;                    // B*768  =  98304
    float* scores  = wsf + 98304;            // B*S    = 128000
    float* attn    = wsf + 226304;           // B*S    = 128000
    float* Dc      = wsf + 354304;           // B*512  =  65536
    float* oscores = wsf + 419840;           // B*S    = 128000

    k_prep<<<832, 256, 0, stream>>>(attnW, decW, attnWb, decWb);
    k_gru<<<BB, 256, 0, stream>>>(dec, h0, embW, embb, Wih, Whh, bih, bhh,
                                  attnW, Wh, out_hidden);
    k_scores<16, 48, H3><<<dim3(8, BB), 256, 0, stream>>>(stat, dyn, attnWb, Wh,
                                                          attnv, scores);
    k_softmax<<<BB, 256, 0, stream>>>(scores, attn);
    k_context<<<BB, 256, 0, stream>>>(attn, stat, decW, Dc);
    k_scores<8, 32, H2><<<dim3(8, BB), 256, 0, stream>>>(stat, nullptr, decWb, Dc,
                                                         decv, oscores);
    k_softmax<<<BB, 256, 0, stream>>>(oscores, out_probs);
}

// Round 3
// 673.949 us; speedup vs baseline: 1.6838x; 1.6838x over previous
//
#include <hip/hip_runtime.h>

#define BB 128
#define SS 1000
#define HH 256
#define H3 768
#define H2 512

typedef unsigned short u16;
typedef short short8 __attribute__((ext_vector_type(8)));
typedef float floatx4 __attribute__((ext_vector_type(4)));
typedef u16 ushort4v __attribute__((ext_vector_type(4)));

__device__ __forceinline__ u16 f2bf(float f) {
    unsigned int x = __float_as_uint(f);
    x += 0x7FFFu + ((x >> 16) & 1u);   // round-to-nearest-even
    return (u16)(x >> 16);
}

// tanh via one v_exp + one v_rcp; exact saturation at +-inf.
__device__ __forceinline__ float fast_tanh(float x) {
    float t = __expf(2.0f * x);
    return 1.0f - 2.0f * __builtin_amdgcn_rcpf(t + 1.0f);
}

__device__ __forceinline__ float sigmoidf(float x) {
    return __builtin_amdgcn_rcpf(1.0f + __expf(-x));
}

// async 16B global -> LDS (dest = wave-uniform base + lane*16)
__device__ __forceinline__ void gl2lds16(const void* src, void* dst) {
    __builtin_amdgcn_global_load_lds(
        (const __attribute__((address_space(1))) unsigned int*)src,
        (__attribute__((address_space(3))) unsigned int*)dst,
        16, 0, 0);
}

// ---------------------------------------------------------------------------
// Pre-convert attn_W [768x768] and dec_W [512x512] f32 -> bf16 in workspace.
// ---------------------------------------------------------------------------
__global__ __launch_bounds__(256) void k_prep(
    const float* __restrict__ aW, const float* __restrict__ dW,
    u16* __restrict__ aWb, u16* __restrict__ dWb)
{
    int idx = (blockIdx.x * 256 + threadIdx.x) * 4;
    const float* src;
    u16* dst;
    if (idx < 589824) { src = aW + idx; dst = aWb + idx; }
    else              { src = dW + (idx - 589824); dst = dWb + (idx - 589824); }
    float4 v = *(const float4*)src;
    ushort4v o = { f2bf(v.x), f2bf(v.y), f2bf(v.z), f2bf(v.w) };
    *(ushort4v*)dst = o;
}

// ---------------------------------------------------------------------------
// embed + GRU cell + hidden out + Wh[b,j] = attn_W[j,512:768]·h_new[b]
// ---------------------------------------------------------------------------
__global__ __launch_bounds__(256) void k_gru(
    const float* __restrict__ dec, const float* __restrict__ h0,
    const float* __restrict__ embW, const float* __restrict__ embb,
    const float* __restrict__ Wih, const float* __restrict__ Whh,
    const float* __restrict__ bih, const float* __restrict__ bhh,
    const float* __restrict__ attnW,
    float* __restrict__ Wh, float* __restrict__ out_hidden)
{
    const int b = blockIdx.x, t = threadIdx.x;
    __shared__ float emb_s[HH], h_s[HH], hn_s[HH];

    const float d0 = dec[b * 2 + 0], d1 = dec[b * 2 + 1];
    emb_s[t] = d0 * embW[t * 2 + 0] + d1 * embW[t * 2 + 1] + embb[t];
    h_s[t] = h0[b * HH + t];
    __syncthreads();

    auto dotrow = [&](const float* Wr, const float* xs) -> float {
        float acc = 0.f;
        const float4* p = (const float4*)Wr;
#pragma unroll 8
        for (int c = 0; c < HH / 4; ++c) {
            float4 w = p[c];
            acc += w.x * xs[c * 4 + 0] + w.y * xs[c * 4 + 1]
                 + w.z * xs[c * 4 + 2] + w.w * xs[c * 4 + 3];
        }
        return acc;
    };

    float gr = dotrow(Wih + (size_t)t * HH, emb_s) + bih[t]
             + dotrow(Whh + (size_t)t * HH, h_s) + bhh[t];
    float r = sigmoidf(gr);

    float gz = dotrow(Wih + (size_t)(HH + t) * HH, emb_s) + bih[HH + t]
             + dotrow(Whh + (size_t)(HH + t) * HH, h_s) + bhh[HH + t];
    float z = sigmoidf(gz);

    float xn = dotrow(Wih + (size_t)(2 * HH + t) * HH, emb_s) + bih[2 * HH + t];
    float hn = dotrow(Whh + (size_t)(2 * HH + t) * HH, h_s) + bhh[2 * HH + t];
    float n = fast_tanh(xn + r * hn);

    float hv = (1.0f - z) * n + z * h_s[t];
    out_hidden[b * HH + t] = hv;
    hn_s[t] = hv;
    __syncthreads();

#pragma unroll
    for (int rr = 0; rr < 3; ++rr) {
        int j = t + rr * HH;
        Wh[b * H3 + j] = dotrow(attnW + (size_t)j * H3 + 2 * HH, hn_s);
    }
}

// ---------------------------------------------------------------------------
// Score GEMM: out[b,s] = sum_j vj[j] * tanh( (A @ Wb^T)[s,j] + addj[b,j] )
// A rows: k<256 from A1 (f32), k>=256 from A2 (f32); bf16-converted in-reg,
// held in VGPRs for ALL of K (read once per row). W staged to LDS in groups
// of 32 j-rows, double-buffered via global_load_lds (async; loads for group
// g+1 issued before compute of group g => barrier drain is cheap).
// XOR swizzle (granule ^= row&7) gives conflict-free ds_read_b128.
// grid = (8, B); block = 256 = 4 waves; wave covers 2 m-tiles of 16 s-rows.
// ---------------------------------------------------------------------------
template <int KSTEPS, int NTILES, int WSTRIDE>
__global__ __launch_bounds__(256, 2) void k_scores(
    const float* __restrict__ A1, const float* __restrict__ A2,
    const u16* __restrict__ Wb, const float* __restrict__ addj,
    const float* __restrict__ vj, float* __restrict__ out)
{
    constexpr int GPR    = KSTEPS * 4;     // 16B granules per j-row
    constexpr int NINSTR = KSTEPS / 2;     // global_load_lds per wave per stage
    constexpr int BUFU16 = 1024 * KSTEPS;  // u16 per buffer (32 rows * GPR * 8)
    constexpr int NG     = NTILES / 2;     // groups of 32 j-rows

    __shared__ u16 smem[2 * BUFU16];

    const int b = blockIdx.y, t = threadIdx.x;
    const int wave = t >> 6, lane = t & 63;
    const int q = lane >> 4, c = lane & 15;
    const int swz = c & 7;
    const int s_base = blockIdx.x * 128 + wave * 32;
    const int kb = q * 8;

    // ---- A fragments, full K, in registers -------------------------------
    short8 afrag[2][KSTEPS];
#pragma unroll
    for (int mt = 0; mt < 2; ++mt) {
        int row = s_base + mt * 16 + c;
        if (row > SS - 1) row = SS - 1;            // tail clamp; writes guarded
        const size_t abase = (size_t)(b * SS + row) * HH;
#pragma unroll
        for (int ks = 0; ks < KSTEPS; ++ks) {
            int k = ks * 32 + kb;
            const float* src = (k < HH) ? (A1 + abase + k) : (A2 + abase + (k - HH));
            float4 u0 = *(const float4*)src;
            float4 u1 = *(const float4*)(src + 4);
            short8 f;
            f[0] = (short)f2bf(u0.x); f[1] = (short)f2bf(u0.y);
            f[2] = (short)f2bf(u0.z); f[3] = (short)f2bf(u0.w);
            f[4] = (short)f2bf(u1.x); f[5] = (short)f2bf(u1.y);
            f[6] = (short)f2bf(u1.z); f[7] = (short)f2bf(u1.w);
            afrag[mt][ks] = f;
        }
    }

    // ---- async stage of one 32-row W group into LDS buffer ----------------
    auto stage = [&](int g, int bufsel) {
        const int jbase = g * 32;
        u16* base = smem + bufsel * BUFU16;
#pragma unroll
        for (int i = 0; i < NINSTR; ++i) {
            int gl = (wave * NINSTR + i) * 64 + lane;   // granule index in buffer
            int r  = gl / GPR;                          // local j-row 0..31
            int p  = gl % GPR;                          // physical granule in row
            int gg = p ^ (r & 7);                       // logical (source) granule
            const u16* src = Wb + (size_t)(jbase + r) * WSTRIDE + gg * 8;
            u16* dst = base + (size_t)(wave * NINSTR + i) * 512;  // uniform/wave
            gl2lds16(src, dst);
        }
    };

    float pout[2][4] = {{0.f, 0.f, 0.f, 0.f}, {0.f, 0.f, 0.f, 0.f}};

    stage(0, 0);
    for (int g = 0; g < NG; ++g) {
        __syncthreads();                       // drains vmcnt: buf[g&1] ready
        if (g + 1 < NG) stage(g + 1, (g + 1) & 1);

        const u16* base = smem + (g & 1) * BUFU16;
        floatx4 acc[2][2] = {{{0.f,0.f,0.f,0.f},{0.f,0.f,0.f,0.f}},
                             {{0.f,0.f,0.f,0.f},{0.f,0.f,0.f,0.f}}};
#pragma unroll
        for (int ks = 0; ks < KSTEPS; ++ks) {
            const int pg = ks * 4 + q;
#pragma unroll
            for (int jt = 0; jt < 2; ++jt) {
                const int paddr = ((jt * 16 + c) * GPR + (pg ^ swz)) * 8;
                short8 wf = *(const short8*)(base + paddr);
                acc[jt][0] = __builtin_amdgcn_mfma_f32_16x16x32_bf16(afrag[0][ks], wf, acc[jt][0], 0, 0, 0);
                acc[jt][1] = __builtin_amdgcn_mfma_f32_16x16x32_bf16(afrag[1][ks], wf, acc[jt][1], 0, 0, 0);
            }
        }
        // epilogue for the 32 j of this group
#pragma unroll
        for (int jt = 0; jt < 2; ++jt) {
            const int j = g * 32 + jt * 16 + c;
            const float aj = addj[b * (NTILES * 16) + j];
            const float vv = vj[j];
#pragma unroll
            for (int r4 = 0; r4 < 4; ++r4) {
                pout[0][r4] += fast_tanh(acc[jt][0][r4] + aj) * vv;
                pout[1][r4] += fast_tanh(acc[jt][1][r4] + aj) * vv;
            }
        }
    }

    // reduce over the 16 lanes of each quad (the j-columns)
#pragma unroll
    for (int mt = 0; mt < 2; ++mt)
#pragma unroll
        for (int r4 = 0; r4 < 4; ++r4)
#pragma unroll
            for (int off = 1; off < 16; off <<= 1)
                pout[mt][r4] += __shfl_xor(pout[mt][r4], off, 64);

    if (c == 0) {
#pragma unroll
        for (int mt = 0; mt < 2; ++mt) {
            const int srow = s_base + mt * 16 + q * 4;
#pragma unroll
            for (int r4 = 0; r4 < 4; ++r4)
                if (srow + r4 < SS) out[b * SS + srow + r4] = pout[mt][r4];
        }
    }
}

// ---------------------------------------------------------------------------
// Softmax over S per batch row; f32 in, f32 out.
// ---------------------------------------------------------------------------
__global__ __launch_bounds__(256) void k_softmax(
    const float* __restrict__ in, float* __restrict__ outf)
{
    const int b = blockIdx.x, t = threadIdx.x;
    __shared__ float red[4];
    const float* rowp = in + b * SS;

    float m = -1e30f;
    for (int s = t; s < SS; s += 256) m = fmaxf(m, rowp[s]);
#pragma unroll
    for (int off = 32; off >= 1; off >>= 1) m = fmaxf(m, __shfl_xor(m, off, 64));
    if ((t & 63) == 0) red[t >> 6] = m;
    __syncthreads();
    m = fmaxf(fmaxf(red[0], red[1]), fmaxf(red[2], red[3]));

    float sum = 0.f;
    for (int s = t; s < SS; s += 256) sum += __expf(rowp[s] - m);
#pragma unroll
    for (int off = 32; off >= 1; off >>= 1) sum += __shfl_xor(sum, off, 64);
    __syncthreads();
    if ((t & 63) == 0) red[t >> 6] = sum;
    __syncthreads();
    sum = red[0] + red[1] + red[2] + red[3];

    const float inv = 1.0f / sum;
    for (int s = t; s < SS; s += 256)
        outf[b * SS + s] = __expf(rowp[s] - m) * inv;
}

// ---------------------------------------------------------------------------
// context[b,h] = sum_s attn[b,s]*static[b,s,h]; Dc[b,j] = dec_W[j,256:512]·ctx[b]
// ---------------------------------------------------------------------------
__global__ __launch_bounds__(256) void k_context(
    const float* __restrict__ attn, const float* __restrict__ stat,
    const float* __restrict__ decW, float* __restrict__ Dc)
{
    const int b = blockIdx.x, t = threadIdx.x;
    __shared__ float attn_s[SS];
    __shared__ float ctx_s[HH];
    for (int s = t; s < SS; s += 256) attn_s[s] = attn[b * SS + s];
    __syncthreads();

    float acc = 0.f;
    const float* base = stat + (size_t)b * SS * HH + t;
#pragma unroll 4
    for (int s = 0; s < SS; ++s) acc += attn_s[s] * base[(size_t)s * HH];
    ctx_s[t] = acc;
    __syncthreads();

#pragma unroll
    for (int rr = 0; rr < 2; ++rr) {
        int j = t + rr * 256;
        float a2 = 0.f;
        const float4* p = (const float4*)(decW + (size_t)j * H2 + HH);
#pragma unroll 8
        for (int cc = 0; cc < HH / 4; ++cc) {
            float4 w = p[cc];
            a2 += w.x * ctx_s[cc * 4 + 0] + w.y * ctx_s[cc * 4 + 1]
                + w.z * ctx_s[cc * 4 + 2] + w.w * ctx_s[cc * 4 + 3];
        }
        Dc[b * H2 + j] = a2;
    }
}

// ---------------------------------------------------------------------------
extern "C" void kernel_launch(void* const* d_in, const int* in_sizes, int n_in,
                              void* d_out, int out_size, void* d_ws, size_t ws_size,
                              hipStream_t stream)
{
    const float* dec   = (const float*)d_in[0];
    const float* h0    = (const float*)d_in[1];
    const float* stat  = (const float*)d_in[2];
    const float* dyn   = (const float*)d_in[3];
    const float* embW  = (const float*)d_in[4];
    const float* embb  = (const float*)d_in[5];
    const float* Wih   = (const float*)d_in[6];
    const float* Whh   = (const float*)d_in[7];
    const float* bih   = (const float*)d_in[8];
    const float* bhh   = (const float*)d_in[9];
    const float* attnW = (const float*)d_in[10];
    const float* attnv = (const float*)d_in[11];
    const float* decW  = (const float*)d_in[12];
    const float* decv  = (const float*)d_in[13];

    float* out        = (float*)d_out;
    float* out_probs  = out;                 // [B, S]
    float* out_hidden = out + BB * SS;       // [1, B, H]

    u16* wsb     = (u16*)d_ws;
    u16* attnWb  = wsb;                      // 768*768 = 589824 u16
    u16* decWb   = wsb + 589824;             // 512*512 = 262144 u16
    float* wsf   = (float*)(wsb + 851968);
    float* Wh      = wsf;                    // B*768
    float* scores  = wsf + 98304;            // B*S
    float* attn    = wsf + 226304;           // B*S
    float* Dc      = wsf + 354304;           // B*512
    float* oscores = wsf + 419840;           // B*S

    k_prep<<<832, 256, 0, stream>>>(attnW, decW, attnWb, decWb);
    k_gru<<<BB, 256, 0, stream>>>(dec, h0, embW, embb, Wih, Whh, bih, bhh,
                                  attnW, Wh, out_hidden);
    k_scores<16, 48, H3><<<dim3(8, BB), 256, 0, stream>>>(stat, dyn, attnWb, Wh,
                                                          attnv, scores);
    k_softmax<<<BB, 256, 0, stream>>>(scores, attn);
    k_context<<<BB, 256, 0, stream>>>(attn, stat, decW, Dc);
    k_scores<8, 32, H2><<<dim3(8, BB), 256, 0, stream>>>(stat, nullptr, decWb, Dc,
                                                         decv, oscores);
    k_softmax<<<BB, 256, 0, stream>>>(oscores, out_probs);
}

// Round 4
// 608.862 us; speedup vs baseline: 1.8638x; 1.1069x over previous
//
#include <hip/hip_runtime.h>

#define BB 128
#define SS 1000
#define HH 256
#define H3 768
#define H2 512
#define NCHUNK 8

typedef unsigned short u16;
typedef short short8 __attribute__((ext_vector_type(8)));
typedef float floatx4 __attribute__((ext_vector_type(4)));
typedef u16 ushort4v __attribute__((ext_vector_type(4)));

__device__ __forceinline__ float bf2f(u16 u) {
    union { unsigned int i; float f; } v;
    v.i = ((unsigned int)u) << 16;
    return v.f;
}

__device__ __forceinline__ u16 f2bf(float f) {
    unsigned int x = __float_as_uint(f);
    x += 0x7FFFu + ((x >> 16) & 1u);   // round-to-nearest-even
    return (u16)(x >> 16);
}

// tanh via one v_exp + one v_rcp; exact saturation at +-inf.
__device__ __forceinline__ float fast_tanh(float x) {
    float t = __expf(2.0f * x);
    return 1.0f - 2.0f * __builtin_amdgcn_rcpf(t + 1.0f);
}

__device__ __forceinline__ float sigmoidf(float x) {
    return __builtin_amdgcn_rcpf(1.0f + __expf(-x));
}

// async 16B global -> LDS (dest = wave-uniform base + lane*16)
__device__ __forceinline__ void gl2lds16(const void* src, void* dst) {
    __builtin_amdgcn_global_load_lds(
        (const __attribute__((address_space(1))) unsigned int*)src,
        (__attribute__((address_space(3))) unsigned int*)dst,
        16, 0, 0);
}

// ---------------------------------------------------------------------------
// Pre-convert attn_W [768x768] and dec_W [512x512] f32 -> bf16 in workspace.
// ---------------------------------------------------------------------------
__global__ __launch_bounds__(256) void k_prep(
    const float* __restrict__ aW, const float* __restrict__ dW,
    u16* __restrict__ aWb, u16* __restrict__ dWb)
{
    int idx = (blockIdx.x * 256 + threadIdx.x) * 4;
    const float* src;
    u16* dst;
    if (idx < 589824) { src = aW + idx; dst = aWb + idx; }
    else              { src = dW + (idx - 589824); dst = dWb + (idx - 589824); }
    float4 v = *(const float4*)src;
    ushort4v o = { f2bf(v.x), f2bf(v.y), f2bf(v.z), f2bf(v.w) };
    *(ushort4v*)dst = o;
}

// ---------------------------------------------------------------------------
// embed + GRU cell + hidden out + Wh[b,j] = attn_W[j,512:768]·h_new[b]
// ---------------------------------------------------------------------------
__global__ __launch_bounds__(256) void k_gru(
    const float* __restrict__ dec, const float* __restrict__ h0,
    const float* __restrict__ embW, const float* __restrict__ embb,
    const float* __restrict__ Wih, const float* __restrict__ Whh,
    const float* __restrict__ bih, const float* __restrict__ bhh,
    const float* __restrict__ attnW,
    float* __restrict__ Wh, float* __restrict__ out_hidden)
{
    const int b = blockIdx.x, t = threadIdx.x;
    __shared__ float emb_s[HH], h_s[HH], hn_s[HH];

    const float d0 = dec[b * 2 + 0], d1 = dec[b * 2 + 1];
    emb_s[t] = d0 * embW[t * 2 + 0] + d1 * embW[t * 2 + 1] + embb[t];
    h_s[t] = h0[b * HH + t];
    __syncthreads();

    auto dotrow = [&](const float* Wr, const float* xs) -> float {
        float acc = 0.f;
        const float4* p = (const float4*)Wr;
#pragma unroll 8
        for (int c = 0; c < HH / 4; ++c) {
            float4 w = p[c];
            acc += w.x * xs[c * 4 + 0] + w.y * xs[c * 4 + 1]
                 + w.z * xs[c * 4 + 2] + w.w * xs[c * 4 + 3];
        }
        return acc;
    };

    float gr = dotrow(Wih + (size_t)t * HH, emb_s) + bih[t]
             + dotrow(Whh + (size_t)t * HH, h_s) + bhh[t];
    float r = sigmoidf(gr);

    float gz = dotrow(Wih + (size_t)(HH + t) * HH, emb_s) + bih[HH + t]
             + dotrow(Whh + (size_t)(HH + t) * HH, h_s) + bhh[HH + t];
    float z = sigmoidf(gz);

    float xn = dotrow(Wih + (size_t)(2 * HH + t) * HH, emb_s) + bih[2 * HH + t];
    float hn = dotrow(Whh + (size_t)(2 * HH + t) * HH, h_s) + bhh[2 * HH + t];
    float n = fast_tanh(xn + r * hn);

    float hv = (1.0f - z) * n + z * h_s[t];
    out_hidden[b * HH + t] = hv;
    hn_s[t] = hv;
    __syncthreads();

#pragma unroll
    for (int rr = 0; rr < 3; ++rr) {
        int j = t + rr * HH;
        Wh[b * H3 + j] = dotrow(attnW + (size_t)j * H3 + 2 * HH, hn_s);
    }
}

// ---------------------------------------------------------------------------
// Score GEMM: out[b,s] = sum_j vj[j] * tanh( (A @ Wb^T)[s,j] + addj[b,j] )
// A held full-K in regs; W double-buffer staged via global_load_lds with XOR
// swizzle. addj/vj preloaded to LDS. Epilogue deferred one group so its VALU
// overlaps the next group's ds_read/MFMA stream. Explicit 1-step ds prefetch.
// grid = (8, B); block = 256 = 4 waves; wave = 2 m-tiles of 16 s-rows.
// ---------------------------------------------------------------------------
template <int KSTEPS, int NTILES, int WSTRIDE>
__global__ __launch_bounds__(256, 2) void k_scores(
    const float* __restrict__ A1, const float* __restrict__ A2,
    const u16* __restrict__ Wb, const float* __restrict__ addj,
    const float* __restrict__ vj, float* __restrict__ out)
{
    constexpr int GPR    = KSTEPS * 4;     // 16B granules per j-row
    constexpr int NINSTR = KSTEPS / 2;     // global_load_lds per wave per stage
    constexpr int BUFU16 = 1024 * KSTEPS;  // u16 per buffer (32 rows * GPR * 8)
    constexpr int NG     = NTILES / 2;     // groups of 32 j-rows
    constexpr int NJ     = NTILES * 16;    // total j

    __shared__ u16 smem[2 * BUFU16];
    __shared__ float aj_s[NJ], vj_s[NJ];

    const int b = blockIdx.y, t = threadIdx.x;
    const int wave = t >> 6, lane = t & 63;
    const int q = lane >> 4, c = lane & 15;
    const int swz = c & 7;
    const int s_base = blockIdx.x * 128 + wave * 32;
    const int kb = q * 8;

    // ---- stage group 0 ASAP ----------------------------------------------
    auto stage = [&](int g, int bufsel) {
        const int jbase = g * 32;
        u16* base = smem + bufsel * BUFU16;
#pragma unroll
        for (int i = 0; i < NINSTR; ++i) {
            int gl = (wave * NINSTR + i) * 64 + lane;   // granule index in buffer
            int r  = gl / GPR;                          // local j-row 0..31
            int p  = gl % GPR;                          // physical granule in row
            int gg = p ^ (r & 7);                       // logical (source) granule
            const u16* src = Wb + (size_t)(jbase + r) * WSTRIDE + gg * 8;
            u16* dst = base + (size_t)(wave * NINSTR + i) * 512;  // uniform/wave
            gl2lds16(src, dst);
        }
    };
    stage(0, 0);

    // ---- preload addj row + v into LDS -----------------------------------
    for (int i = t; i < NJ; i += 256) {
        aj_s[i] = addj[b * NJ + i];
        vj_s[i] = vj[i];
    }

    // ---- A fragments, full K, in registers -------------------------------
    short8 afrag[2][KSTEPS];
#pragma unroll
    for (int mt = 0; mt < 2; ++mt) {
        int row = s_base + mt * 16 + c;
        if (row > SS - 1) row = SS - 1;            // tail clamp; writes guarded
        const size_t abase = (size_t)(b * SS + row) * HH;
#pragma unroll
        for (int ks = 0; ks < KSTEPS; ++ks) {
            int k = ks * 32 + kb;
            const float* src = (k < HH) ? (A1 + abase + k) : (A2 + abase + (k - HH));
            float4 u0 = *(const float4*)src;
            float4 u1 = *(const float4*)(src + 4);
            short8 f;
            f[0] = (short)f2bf(u0.x); f[1] = (short)f2bf(u0.y);
            f[2] = (short)f2bf(u0.z); f[3] = (short)f2bf(u0.w);
            f[4] = (short)f2bf(u1.x); f[5] = (short)f2bf(u1.y);
            f[6] = (short)f2bf(u1.z); f[7] = (short)f2bf(u1.w);
            afrag[mt][ks] = f;
        }
    }

    float pout[2][4] = {{0.f, 0.f, 0.f, 0.f}, {0.f, 0.f, 0.f, 0.f}};
    floatx4 accB[2][2][2];                    // [sel][jt][mt]

    auto epilogue = [&](int gg) {
        floatx4 (*ac)[2] = accB[gg & 1];
#pragma unroll
        for (int jt = 0; jt < 2; ++jt) {
            const int j = gg * 32 + jt * 16 + c;
            const float aj = aj_s[j];
            const float vv = vj_s[j];
#pragma unroll
            for (int r4 = 0; r4 < 4; ++r4) {
                pout[0][r4] += fast_tanh(ac[jt][0][r4] + aj) * vv;
                pout[1][r4] += fast_tanh(ac[jt][1][r4] + aj) * vv;
            }
        }
    };

    int have = 0, gP = 0;
    for (int g = 0; g < NG; ++g) {
        __syncthreads();                       // buf[g&1] staged; old reads done
        if (g + 1 < NG) stage(g + 1, (g + 1) & 1);

        const u16* base = smem + (g & 1) * BUFU16;
        floatx4 (*acc)[2] = accB[g & 1];
#pragma unroll
        for (int jt = 0; jt < 2; ++jt)
#pragma unroll
            for (int mt = 0; mt < 2; ++mt)
                acc[jt][mt] = (floatx4){0.f, 0.f, 0.f, 0.f};

        auto ldsrd = [&](int ks, int jt) -> short8 {
            const int paddr = ((jt * 16 + c) * GPR + ((ks * 4 + q) ^ swz)) * 8;
            return *(const short8*)(base + paddr);
        };

        short8 wf0 = ldsrd(0, 0);
        short8 wf1 = ldsrd(0, 1);

        if (have) epilogue(gP);               // overlaps with this group's MFMA

#pragma unroll
        for (int ks = 0; ks < KSTEPS; ++ks) {
            short8 nf0, nf1;
            if (ks + 1 < KSTEPS) { nf0 = ldsrd(ks + 1, 0); nf1 = ldsrd(ks + 1, 1); }
            acc[0][0] = __builtin_amdgcn_mfma_f32_16x16x32_bf16(afrag[0][ks], wf0, acc[0][0], 0, 0, 0);
            acc[0][1] = __builtin_amdgcn_mfma_f32_16x16x32_bf16(afrag[1][ks], wf0, acc[0][1], 0, 0, 0);
            acc[1][0] = __builtin_amdgcn_mfma_f32_16x16x32_bf16(afrag[0][ks], wf1, acc[1][0], 0, 0, 0);
            acc[1][1] = __builtin_amdgcn_mfma_f32_16x16x32_bf16(afrag[1][ks], wf1, acc[1][1], 0, 0, 0);
            wf0 = nf0; wf1 = nf1;
        }
        gP = g; have = 1;
    }
    epilogue(gP);

    // reduce over the 16 lanes of each quad (the j-columns)
#pragma unroll
    for (int mt = 0; mt < 2; ++mt)
#pragma unroll
        for (int r4 = 0; r4 < 4; ++r4)
#pragma unroll
            for (int off = 1; off < 16; off <<= 1)
                pout[mt][r4] += __shfl_xor(pout[mt][r4], off, 64);

    if (c == 0) {
#pragma unroll
        for (int mt = 0; mt < 2; ++mt) {
            const int srow = s_base + mt * 16 + q * 4;
#pragma unroll
            for (int r4 = 0; r4 < 4; ++r4)
                if (srow + r4 < SS) out[b * SS + srow + r4] = pout[mt][r4];
        }
    }
}

// ---------------------------------------------------------------------------
// Softmax over S per batch row; f32 in, f32 out.
// ---------------------------------------------------------------------------
__global__ __launch_bounds__(256) void k_softmax(
    const float* __restrict__ in, float* __restrict__ outf)
{
    const int b = blockIdx.x, t = threadIdx.x;
    __shared__ float red[4];
    const float* rowp = in + b * SS;

    float m = -1e30f;
    for (int s = t; s < SS; s += 256) m = fmaxf(m, rowp[s]);
#pragma unroll
    for (int off = 32; off >= 1; off >>= 1) m = fmaxf(m, __shfl_xor(m, off, 64));
    if ((t & 63) == 0) red[t >> 6] = m;
    __syncthreads();
    m = fmaxf(fmaxf(red[0], red[1]), fmaxf(red[2], red[3]));

    float sum = 0.f;
    for (int s = t; s < SS; s += 256) sum += __expf(rowp[s] - m);
#pragma unroll
    for (int off = 32; off >= 1; off >>= 1) sum += __shfl_xor(sum, off, 64);
    __syncthreads();
    if ((t & 63) == 0) red[t >> 6] = sum;
    __syncthreads();
    sum = red[0] + red[1] + red[2] + red[3];

    const float inv = 1.0f / sum;
    for (int s = t; s < SS; s += 256)
        outf[b * SS + s] = __expf(rowp[s] - m) * inv;
}

// ---------------------------------------------------------------------------
// Context partials: chunk of 125 s-rows per block; wave-per-row float4 loads.
// part[chunk][b][h] = sum_{s in chunk} attn[b,s] * static[b,s,h]
// grid = (NCHUNK, B), 256 threads.
// ---------------------------------------------------------------------------
__global__ __launch_bounds__(256) void k_ctx_part(
    const float* __restrict__ attn, const float* __restrict__ stat,
    float* __restrict__ part)
{
    constexpr int CH = SS / NCHUNK;            // 125
    const int chunk = blockIdx.x, b = blockIdx.y, t = threadIdx.x;
    const int wave = t >> 6, lane = t & 63;

    __shared__ float attn_s[CH];
    __shared__ float red[4][HH];

    for (int i = t; i < CH; i += 256) attn_s[i] = attn[b * SS + chunk * CH + i];
    __syncthreads();

    float4 acc = {0.f, 0.f, 0.f, 0.f};
    const float* base = stat + ((size_t)(b * SS + chunk * CH) * HH) + lane * 4;
#pragma unroll 4
    for (int i = wave; i < CH; i += 4) {
        float w = attn_s[i];
        float4 v = *(const float4*)(base + (size_t)i * HH);
        acc.x += w * v.x; acc.y += w * v.y; acc.z += w * v.z; acc.w += w * v.w;
    }
    *(float4*)(&red[wave][lane * 4]) = acc;
    __syncthreads();

    part[(size_t)(chunk * BB + b) * HH + t] =
        red[0][t] + red[1][t] + red[2][t] + red[3][t];
}

// ---------------------------------------------------------------------------
// Reduce partials -> context; Dc[b,j] = dec_W[j,256:512]·context[b] (bf16 W).
// grid = B, 256 threads.
// ---------------------------------------------------------------------------
__global__ __launch_bounds__(256) void k_ctx_red(
    const float* __restrict__ part, const u16* __restrict__ decWb,
    float* __restrict__ Dc)
{
    const int b = blockIdx.x, t = threadIdx.x;
    __shared__ float ctx_s[HH];

    float s = 0.f;
#pragma unroll
    for (int c = 0; c < NCHUNK; ++c) s += part[(size_t)(c * BB + b) * HH + t];
    ctx_s[t] = s;
    __syncthreads();

#pragma unroll
    for (int rr = 0; rr < 2; ++rr) {
        int j = t + rr * 256;
        float a2 = 0.f;
        const short8* p = (const short8*)(decWb + (size_t)j * H2 + HH);
#pragma unroll 4
        for (int cc = 0; cc < HH / 8; ++cc) {
            short8 w = p[cc];
#pragma unroll
            for (int k = 0; k < 8; ++k) a2 += bf2f((u16)w[k]) * ctx_s[cc * 8 + k];
        }
        Dc[b * H2 + j] = a2;
    }
}

// ---------------------------------------------------------------------------
extern "C" void kernel_launch(void* const* d_in, const int* in_sizes, int n_in,
                              void* d_out, int out_size, void* d_ws, size_t ws_size,
                              hipStream_t stream)
{
    const float* dec   = (const float*)d_in[0];
    const float* h0    = (const float*)d_in[1];
    const float* stat  = (const float*)d_in[2];
    const float* dyn   = (const float*)d_in[3];
    const float* embW  = (const float*)d_in[4];
    const float* embb  = (const float*)d_in[5];
    const float* Wih   = (const float*)d_in[6];
    const float* Whh   = (const float*)d_in[7];
    const float* bih   = (const float*)d_in[8];
    const float* bhh   = (const float*)d_in[9];
    const float* attnW = (const float*)d_in[10];
    const float* attnv = (const float*)d_in[11];
    const float* decW  = (const float*)d_in[12];
    const float* decv  = (const float*)d_in[13];

    float* out        = (float*)d_out;
    float* out_probs  = out;                 // [B, S]
    float* out_hidden = out + BB * SS;       // [1, B, H]

    u16* wsb     = (u16*)d_ws;
    u16* attnWb  = wsb;                      // 768*768 = 589824 u16
    u16* decWb   = wsb + 589824;             // 512*512 = 262144 u16
    float* wsf   = (float*)(wsb + 851968);
    float* Wh      = wsf;                    // B*768   =  98304
    float* scores  = wsf + 98304;            // B*S     = 128000
    float* attn    = wsf + 226304;           // B*S     = 128000
    float* Dc      = wsf + 354304;           // B*512   =  65536
    float* oscores = wsf + 419840;           // B*S     = 128000
    float* ctxpart = wsf + 547840;           // 8*B*256 = 262144

    k_prep<<<832, 256, 0, stream>>>(attnW, decW, attnWb, decWb);
    k_gru<<<BB, 256, 0, stream>>>(dec, h0, embW, embb, Wih, Whh, bih, bhh,
                                  attnW, Wh, out_hidden);
    k_scores<16, 48, H3><<<dim3(8, BB), 256, 0, stream>>>(stat, dyn, attnWb, Wh,
                                                          attnv, scores);
    k_softmax<<<BB, 256, 0, stream>>>(scores, attn);
    k_ctx_part<<<dim3(NCHUNK, BB), 256, 0, stream>>>(attn, stat, ctxpart);
    k_ctx_red<<<BB, 256, 0, stream>>>(ctxpart, decWb, Dc);
    k_scores<8, 32, H2><<<dim3(8, BB), 256, 0, stream>>>(stat, nullptr, decWb, Dc,
                                                         decv, oscores);
    k_softmax<<<BB, 256, 0, stream>>>(oscores, out_probs);
}